// Round 4
// baseline (121.754 us; speedup 1.0000x reference)
//
#include <hip/hip_runtime.h>
#include <hip/hip_bf16.h>
#include <math.h>

// Problem constants: B=32, L=128, D=512, Qn=16, N=512, P=64
#define DD    512
#define QN    16
#define NTOK  4096
#define MEXT  4112           // NTOK + QN
#define NGRP  512
#define PP    64
#define NB    576            // padded B rows: 512 Wv + 16 score + 48 pad (9 tiles)
#define SCALE 0.04419417382415922f   // 1/sqrt(512)

typedef __bf16 bf16x8 __attribute__((ext_vector_type(8)));
typedef float  f32x4  __attribute__((ext_vector_type(4)));

static __device__ __forceinline__ ushort f2bf(float f) {
    __hip_bfloat16 h = __float2bfloat16(f);
    return *reinterpret_cast<ushort*>(&h);
}
// unpack 2 packed bf16 (little-endian: low ushort = element 0) to fp32
static __device__ __forceinline__ float2 bfp2f2(unsigned int v) {
    float2 r;
    r.x = __uint_as_float(v << 16);
    r.y = __uint_as_float(v & 0xffff0000u);
    return r;
}
// async global->LDS, 16B per lane (HW: wave-uniform LDS base + lane*16)
static __device__ __forceinline__ void gload16(const void* g, void* l) {
    __builtin_amdgcn_global_load_lds(
        (const __attribute__((address_space(1))) void*)g,
        (__attribute__((address_space(3))) void*)l, 16, 0, 0);
}
// cvt 8 fp32 -> 8 bf16, 16B store to LDS byte address
static __device__ __forceinline__ void packstore(char* dst, float4 a, float4 b) {
    ushort o[8];
    o[0]=f2bf(a.x); o[1]=f2bf(a.y); o[2]=f2bf(a.z); o[3]=f2bf(a.w);
    o[4]=f2bf(b.x); o[5]=f2bf(b.y); o[6]=f2bf(b.z); o[7]=f2bf(b.w);
    *(uint4*)dst = *(const uint4*)o;
}

// ---------------------------------------------------------------------------
// pack_b: slim pack (X-cast eliminated; k2 reads patch fp32 directly).
//  [0,64)    : Bb rows 0..511   = bf16(Wv^T)  (64x64 LDS-tile transpose)
//  [64,76)   : Bb rows 528..575 = 0
//  [76,208)  : Bb rows 512..527 = bf16(Wk @ Q0^T), + c0[q] = bk.Q0[q]
//  [208,240) : xtail[128][512] fp32 = [Q0 ; zeros]  (k2 A-tail source)
// ---------------------------------------------------------------------------
__global__ __launch_bounds__(256) void pack_b(
    const float* __restrict__ query,
    const float* __restrict__ Wv, const float* __restrict__ Wk,
    const float* __restrict__ bk,
    ushort* __restrict__ Bb, float* __restrict__ c0, float* __restrict__ xtail)
{
    __shared__ float T[64][65];
    const int b = blockIdx.x;
    const int tid = threadIdx.x;
    if (b < 64) {                         // Wv transpose, 64x64 tile
        const int k0 = (b >> 3) * 64, n0 = (b & 7) * 64;
#pragma unroll
        for (int j = 0; j < 16; ++j) {
            const int idx = tid + j * 256;
            const int r = idx >> 6, c = idx & 63;
            T[r][c] = Wv[(size_t)(k0 + r) * DD + n0 + c];
        }
        __syncthreads();
#pragma unroll
        for (int j = 0; j < 16; ++j) {
            const int idx = tid + j * 256;
            const int r = idx >> 6, c = idx & 63;
            Bb[(size_t)(n0 + r) * DD + k0 + c] = f2bf(T[c][r]);
        }
    } else if (b < 76) {                  // zero rows 528..575
        const int e0 = (b - 64) * 2048 + tid * 8;
        *(uint4*)&Bb[(size_t)528 * DD + e0] = make_uint4(0, 0, 0, 0);
    } else if (b < 208) {                 // score B-rows + c0
        const int wave = tid >> 6, lane = tid & 63;
        const int g = (b - 76) * 4 + wave;
        if (g < DD) {
            const int e = g;
            float x[8];
#pragma unroll
            for (int j = 0; j < 8; ++j) x[j] = Wk[e * DD + j * 64 + lane];
            for (int q = 0; q < QN; ++q) {
                float s = 0.f;
#pragma unroll
                for (int j = 0; j < 8; ++j) s += x[j] * query[q * DD + j * 64 + lane];
#pragma unroll
                for (int off = 32; off > 0; off >>= 1) s += __shfl_down(s, off, 64);
                if (lane == 0) Bb[(size_t)(DD + q) * DD + e] = f2bf(s);
            }
        } else if (g < DD + QN) {
            const int q = g - DD;
            float s = 0.f;
#pragma unroll
            for (int j = 0; j < 8; ++j)
                s += bk[j * 64 + lane] * query[q * DD + j * 64 + lane];
#pragma unroll
            for (int off = 32; off > 0; off >>= 1) s += __shfl_down(s, off, 64);
            if (lane == 0) c0[q] = s;
        }
    } else {                              // xtail fp32: rows 0..15 = Q0, rest 0
        const int e0 = (b - 208) * 2048 + tid * 8;
        const int row = e0 >> 9, c = e0 & 511;
        float4 v0 = make_float4(0.f, 0.f, 0.f, 0.f), v1 = v0;
        if (row < QN) {
            v0 = *(const float4*)&query[(size_t)row * DD + c];
            v1 = *(const float4*)&query[(size_t)row * DD + c + 4];
        }
        *(float4*)&xtail[e0]     = v0;
        *(float4*)&xtail[e0 + 4] = v1;
    }
}

// ---------------------------------------------------------------------------
// K2: fused MFMA GEMM  C[4224 x 576] = bf16(X) @ Bb^T
//   X rows 0..4095 = patch (fp32, cast in staging); 4096..4223 = xtail.
//   cols 0..511 -> VpH bf16 (+ bv);  cols 512..527 -> S fp32 ((acc+c0)*SCALE)
// 64x64 tile, 4 waves, BK=64, 16x16x32 bf16 MFMA, grid (9,66).
// 2-phase double-buffered pipeline (T3-min + T14): issue next-tile X fp32
// loads + B gload_lds BEFORE the MFMA cluster, cvt+ds_write X AFTER it,
// one __syncthreads per K-step. A-side: reg-staged, swizzled ds_write
// (byte ^= (row&7)<<4). B-side: gload_lds w=16, linear dest, pre-swizzled
// source (verified R3). Same XOR on all read paths.
// ---------------------------------------------------------------------------
__global__ __launch_bounds__(256) void k2_mfma(
    const float* __restrict__ patch, const float* __restrict__ xtail,
    const ushort* __restrict__ Bb,
    const float* __restrict__ bv, const float* __restrict__ c0,
    ushort* __restrict__ VpH, float* __restrict__ S)
{
    __shared__ __align__(16) ushort Xs[2][4096];   // 2 x 8KB, swizzled
    __shared__ __align__(16) ushort Bs[2][4096];
    const int tid = threadIdx.x;
    const int rowBase = blockIdx.y * 64;
    const int colBase = blockIdx.x * 64;
    const int wave = tid >> 6, lane = tid & 63;
    const int wm = (wave >> 1) * 32, wn = (wave & 1) * 32;
    const int lr = lane & 15;
    const int quad = lane >> 4;

    // A staging: lane owns rows r0, r0+32 at fp32 cols c8..c8+7 of each K-tile
    const int r0 = tid >> 3;
    const int r1 = r0 + 32;
    const int c8 = (tid & 7) * 8;
    const int row0 = rowBase + r0, row1 = rowBase + r1;
    const float* s0 = ((row0 < NTOK) ? &patch[(size_t)row0 * DD]
                                     : &xtail[(size_t)(row0 - NTOK) * DD]) + c8;
    const float* s1 = ((row1 < NTOK) ? &patch[(size_t)row1 * DD]
                                     : &xtail[(size_t)(row1 - NTOK) * DD]) + c8;
    const int xw0 = (r0 * 128 + c8 * 2) ^ ((r0 & 7) << 4);   // LDS byte, swizzled
    const int xw1 = (r1 * 128 + c8 * 2) ^ ((r1 & 7) << 4);

    // B staging: 2 x gload16 per K-step, linear LDS dest + pre-swizzled source
    const int L0 = tid * 16;
    const int L1 = 4096 + tid * 16;
    const int br0 = L0 >> 7, bc0 = (L0 & 127) ^ ((br0 & 7) << 4);
    const int br1 = L1 >> 7, bc1 = (L1 & 127) ^ ((br1 & 7) << 4);
    const char* bsrc0 = (const char*)&Bb[(size_t)(colBase + br0) * DD] + bc0;
    const char* bsrc1 = (const char*)&Bb[(size_t)(colBase + br1) * DD] + bc1;

    char* XsB = (char*)Xs;
    char* BsB = (char*)Bs;

    f32x4 acc[2][2];
    const f32x4 zero = {0.f, 0.f, 0.f, 0.f};
#pragma unroll
    for (int i = 0; i < 2; ++i) { acc[i][0] = zero; acc[i][1] = zero; }

    float4 xa, xb, xc, xd;
    // prologue: stage K-step 0 into buf 0
    xa = *(const float4*)s0; xb = *(const float4*)(s0 + 4);
    xc = *(const float4*)s1; xd = *(const float4*)(s1 + 4);
    gload16(bsrc0, BsB + L0);
    gload16(bsrc1, BsB + L1);
    packstore(XsB + xw0, xa, xb);
    packstore(XsB + xw1, xc, xd);
    __syncthreads();

#pragma unroll
    for (int t = 0; t < 8; ++t) {
        const int buf = t & 1, nxt = buf ^ 1;
        const int kf = (t + 1) * 64;           // next K-tile fp32 col offset
        if (t < 7) {                            // issue-early (T14)
            xa = *(const float4*)(s0 + kf); xb = *(const float4*)(s0 + kf + 4);
            xc = *(const float4*)(s1 + kf); xd = *(const float4*)(s1 + kf + 4);
            gload16(bsrc0 + kf * 2, BsB + nxt * 8192 + L0);
            gload16(bsrc1 + kf * 2, BsB + nxt * 8192 + L1);
        }
        const int BF = buf * 8192;
#pragma unroll
        for (int kc = 0; kc < 2; ++kc) {
            bf16x8 af[2], bfr[2];
#pragma unroll
            for (int m = 0; m < 2; ++m) {
                const int ar = wm + m * 16 + lr;
                const int ab = (ar * 128 + kc * 64 + quad * 16) ^ ((ar & 7) << 4);
                af[m] = *(const bf16x8*)(XsB + BF + ab);
            }
#pragma unroll
            for (int u = 0; u < 2; ++u) {
                const int br = wn + u * 16 + lr;
                const int bb = (br * 128 + kc * 64 + quad * 16) ^ ((br & 7) << 4);
                bfr[u] = *(const bf16x8*)(BsB + BF + bb);
            }
#pragma unroll
            for (int mt = 0; mt < 2; ++mt)
#pragma unroll
                for (int nt = 0; nt < 2; ++nt)
                    acc[mt][nt] = __builtin_amdgcn_mfma_f32_16x16x32_bf16(
                        af[mt], bfr[nt], acc[mt][nt], 0, 0, 0);
        }
        if (t < 7) {                            // write-late (T14)
            packstore(XsB + nxt * 8192 + xw0, xa, xb);
            packstore(XsB + nxt * 8192 + xw1, xc, xd);
        }
        __syncthreads();
    }

    // epilogue: C/D layout col = lane&15, row = quad*4 + r (m89/m91)
#pragma unroll
    for (int nt = 0; nt < 2; ++nt) {
        const int col = colBase + wn + nt * 16 + lr;
        const bool isV = (col < DD);
        const bool isS = (col >= DD) && (col < DD + QN);
        const float badd = isV ? bv[col] : (isS ? c0[col - DD] : 0.f);
#pragma unroll
        for (int mt = 0; mt < 2; ++mt) {
#pragma unroll
            for (int r = 0; r < 4; ++r) {
                const int row = rowBase + wm + mt * 16 + quad * 4 + r;
                if (row < MEXT) {
                    const float v = acc[mt][nt][r];
                    if (isV)      VpH[(size_t)row * DD + col] = f2bf(v + badd);
                    else if (isS) S[row * QN + (col - DD)] = (v + badd) * SCALE;
                }
            }
        }
    }
}

// ---------------------------------------------------------------------------
// K4: per-group aggregation. Vp gathered as bf16 (4.2 MB, L2/L3-resident).
// Weights p-major in LDS (scT[p][q]) -> broadcast float4 reads, conflict-free.
// Gather loop 8-deep: issue 8 independent row loads before consuming, to
// cover L2/L3 latency at this kernel's ~2 waves/SIMD occupancy.
// ---------------------------------------------------------------------------
__global__ __launch_bounds__(256) void k4_agg(
    const ushort* __restrict__ VpH,    // MEXT x D bf16 (rows >= NTOK are VQ)
    const float* __restrict__ S,       // MEXT x QN
    const int* __restrict__ indices,
    const void* __restrict__ pmask,
    const float* __restrict__ Wf, const float* __restrict__ bf,
    float* __restrict__ out)
{
    __shared__ int   idxs[PP];
    __shared__ int   mval[PP];
    __shared__ int   cidx[PP + 8];
    __shared__ int   cp[PP + 8];
    __shared__ float scT[PP + 2][QN];  // row0=self, 1..64=gathered, 65=zero pad
    __shared__ float red[QN][4];
    __shared__ float fwq[QN];
    __shared__ int   cntS;

    const int n = blockIdx.x;
    const int tid = threadIdx.x;

    // pos_mask storage-width detection (wave-uniform)
    const unsigned int* mw = (const unsigned int*)pmask;
    bool four = true;
#pragma unroll
    for (int i = 0; i < 16; ++i) {
        const unsigned int v = mw[i];
        four = four && (v == 0u || v == 1u || v == 0x3F800000u);
    }

    if (tid < PP) {
        idxs[tid] = indices[n * PP + tid];
        int mv;
        if (four) mv = (mw[n * PP + tid] != 0u);
        else      mv = (((const unsigned char*)pmask)[n * PP + tid] != 0);
        mval[tid] = mv;
        const bool a = (mv != 0);
        const unsigned long long m = __ballot(a);
        const int pos = __popcll(m & ((1ull << tid) - 1ull));
        if (a) { cidx[pos] = idxs[tid]; cp[pos] = tid; }
        if (tid == 0) cntS = (int)__popcll(m);
    }
    __syncthreads();

    // gather scores (p-major), full 1024-entry fill
    for (int e = tid; e < QN * PP; e += 256) {
        const int p = e >> 4, q = e & 15;
        scT[p + 1][q] = mval[p] ? S[idxs[p] * QN + q] : -INFINITY;
    }
    if (tid < QN) scT[0][tid] = S[(NTOK + tid) * QN + tid];   // s_self[q]
    __syncthreads();

    if (tid < 8) { cidx[cntS + tid] = 0; cp[cntS + tid] = PP; }  // pad entries
    if (tid < QN) {                                  // softmax over 65 per q
        const int q = tid;
        float m = -INFINITY;
        for (int j = 0; j <= PP; ++j) m = fmaxf(m, scT[j][q]);
        float s = 0.f;
        for (int j = 0; j <= PP; ++j) { const float e = __expf(scT[j][q] - m); scT[j][q] = e; s += e; }
        const float inv = 1.f / s;
        for (int j = 0; j <= PP; ++j) scT[j][q] *= inv;
        scT[PP + 1][q] = 0.f;                        // pad weight = 0
    }
    __syncthreads();

    const int cnt8 = (cntS + 7) & ~7;
    const int d0 = tid * 2;
    float pt[QN][2];
    {
        float2 vq[QN];
#pragma unroll
        for (int q = 0; q < QN; ++q)
            vq[q] = bfp2f2(*(const unsigned int*)&VpH[(size_t)(NTOK + q) * DD + d0]);
#pragma unroll
        for (int q = 0; q < QN; ++q) {
            const float w0 = scT[0][q];
            pt[q][0] = w0 * vq[q].x;
            pt[q][1] = w0 * vq[q].y;
        }
    }
    for (int j0 = 0; j0 < cnt8; j0 += 8) {
        float2 v[8]; int p[8];
#pragma unroll
        for (int pi = 0; pi < 8; ++pi) {
            v[pi] = bfp2f2(*(const unsigned int*)&VpH[(size_t)cidx[j0 + pi] * DD + d0]);
            p[pi] = cp[j0 + pi] + 1;
        }
#pragma unroll
        for (int pi = 0; pi < 8; ++pi) {
            const float4 wa = *(const float4*)&scT[p[pi]][0];
            const float4 wb = *(const float4*)&scT[p[pi]][4];
            const float4 wc = *(const float4*)&scT[p[pi]][8];
            const float4 wd = *(const float4*)&scT[p[pi]][12];
            const float vx = v[pi].x, vy = v[pi].y;
            pt[ 0][0] += wa.x*vx; pt[ 0][1] += wa.x*vy;
            pt[ 1][0] += wa.y*vx; pt[ 1][1] += wa.y*vy;
            pt[ 2][0] += wa.z*vx; pt[ 2][1] += wa.z*vy;
            pt[ 3][0] += wa.w*vx; pt[ 3][1] += wa.w*vy;
            pt[ 4][0] += wb.x*vx; pt[ 4][1] += wb.x*vy;
            pt[ 5][0] += wb.y*vx; pt[ 5][1] += wb.y*vy;
            pt[ 6][0] += wb.z*vx; pt[ 6][1] += wb.z*vy;
            pt[ 7][0] += wb.w*vx; pt[ 7][1] += wb.w*vy;
            pt[ 8][0] += wc.x*vx; pt[ 8][1] += wc.x*vy;
            pt[ 9][0] += wc.y*vx; pt[ 9][1] += wc.y*vy;
            pt[10][0] += wc.z*vx; pt[10][1] += wc.z*vy;
            pt[11][0] += wc.w*vx; pt[11][1] += wc.w*vy;
            pt[12][0] += wd.x*vx; pt[12][1] += wd.x*vy;
            pt[13][0] += wd.y*vx; pt[13][1] += wd.y*vy;
            pt[14][0] += wd.z*vx; pt[14][1] += wd.z*vy;
            pt[15][0] += wd.w*vx; pt[15][1] += wd.w*vy;
        }
    }

    // fusion logits f[q] = pt[q,:] . Wf + bf
    const float wf0 = Wf[d0], wf1 = Wf[d0 + 1];
    const int wid = tid >> 6, lane = tid & 63;
#pragma unroll
    for (int q = 0; q < QN; ++q) {
        float s = pt[q][0] * wf0 + pt[q][1] * wf1;
#pragma unroll
        for (int off = 32; off > 0; off >>= 1) s += __shfl_down(s, off, 64);
        if (lane == 0) red[q][wid] = s;
    }
    __syncthreads();
    if (tid == 0) {
        float f[QN];
        float m = -INFINITY;
#pragma unroll
        for (int q = 0; q < QN; ++q) {
            f[q] = red[q][0] + red[q][1] + red[q][2] + red[q][3] + bf[0];
            m = fmaxf(m, f[q]);
        }
        float ssum = 0.f;
#pragma unroll
        for (int q = 0; q < QN; ++q) { f[q] = __expf(f[q] - m); ssum += f[q]; }
        const float inv = 1.f / ssum;
#pragma unroll
        for (int q = 0; q < QN; ++q) fwq[q] = f[q] * inv;
    }
    __syncthreads();

    float o0 = 0.f, o1 = 0.f;
#pragma unroll
    for (int q = 0; q < QN; ++q) {
        const float w = fwq[q];
        o0 += pt[q][0] * w;
        o1 += pt[q][1] * w;
    }
    *(float2*)&out[(size_t)n * DD + d0] = make_float2(o0, o1);
}

// ---------------------------------------------------------------------------
extern "C" void kernel_launch(void* const* d_in, const int* in_sizes, int n_in,
                              void* d_out, int out_size, void* d_ws, size_t ws_size,
                              hipStream_t stream)
{
    const float* patch   = (const float*)d_in[0];
    const float* query   = (const float*)d_in[1];
    const float* Wk      = (const float*)d_in[2];
    const float* bk      = (const float*)d_in[3];
    const float* Wv      = (const float*)d_in[4];
    const float* bv      = (const float*)d_in[5];
    const float* Wf      = (const float*)d_in[6];
    const float* bf      = (const float*)d_in[7];
    const int*   indices = (const int*)d_in[8];
    const void*  pmask   = d_in[9];
    float* out = (float*)d_out;

    // ws: VpH bf16[MEXT*DD] | S f32[MEXT*QN] | c0 f32[16]
    //     | Bb bf16[NB*DD] | xtail f32[128*DD]        (~5.3 MB of 256 MiB ws)
    ushort* VpH   = (ushort*)d_ws;
    float*  S     = (float*)(VpH + (size_t)MEXT * DD);
    float*  c0    = S + (size_t)MEXT * QN;
    ushort* Bb    = (ushort*)(c0 + 16);
    float*  xtail = (float*)(Bb + (size_t)NB * DD);

    pack_b<<<dim3(240), dim3(256), 0, stream>>>(query, Wv, Wk, bk, Bb, c0, xtail);
    k2_mfma<<<dim3(9, 66), dim3(256), 0, stream>>>(patch, xtail, Bb, bv, c0, VpH, S);
    k4_agg <<<dim3(NGRP), dim3(256), 0, stream>>>(VpH, S, indices, pmask, Wf, bf, out);
}

// Round 5
// 120.172 us; speedup vs baseline: 1.0132x; 1.0132x over previous
//
#include <hip/hip_runtime.h>
#include <hip/hip_bf16.h>
#include <math.h>

// Problem constants: B=32, L=128, D=512, Qn=16, N=512, P=64
#define DD    512
#define QN    16
#define NTOK  4096
#define MEXT  4112           // NTOK + QN
#define MPAD  4224           // 66 * 64
#define NGRP  512
#define PP    64
#define NB    576            // padded B rows: 512 Wv + 16 score + 48 pad (9 tiles)
#define SCALE 0.04419417382415922f   // 1/sqrt(512)

typedef __bf16 bf16x8 __attribute__((ext_vector_type(8)));
typedef float  f32x4  __attribute__((ext_vector_type(4)));

static __device__ __forceinline__ ushort f2bf(float f) {
    __hip_bfloat16 h = __float2bfloat16(f);
    return *reinterpret_cast<ushort*>(&h);
}
// unpack 2 packed bf16 (little-endian: low ushort = element 0) to fp32
static __device__ __forceinline__ float2 bfp2f2(unsigned int v) {
    float2 r;
    r.x = __uint_as_float(v << 16);
    r.y = __uint_as_float(v & 0xffff0000u);
    return r;
}
// async global->LDS, 16B per lane (HW: wave-uniform LDS base + lane*16)
static __device__ __forceinline__ void gload16(const void* g, void* l) {
    __builtin_amdgcn_global_load_lds(
        (const __attribute__((address_space(1))) void*)g,
        (__attribute__((address_space(3))) void*)l, 16, 0, 0);
}

// ---------------------------------------------------------------------------
// pack_all: one kernel, block-range dispatch (no cross-range dependencies).
//  [0,1056)    : Xb = bf16([patch ; Q0 ; zeros])              (4224 x 512)
//  [1056,1120) : Bb rows 0..511   = bf16(Wv^T)  (64x64 LDS-tile transpose)
//  [1120,1132) : Bb rows 528..575 = 0
//  [1132,1264) : Bb rows 512..527 = bf16(Wk @ Q0^T), + c0[q] = bk.Q0[q]
// (R3-verified version)
// ---------------------------------------------------------------------------
__global__ __launch_bounds__(256) void pack_all(
    const float* __restrict__ patch, const float* __restrict__ query,
    const float* __restrict__ Wv, const float* __restrict__ Wk,
    const float* __restrict__ bk,
    ushort* __restrict__ Xb, ushort* __restrict__ Bb, float* __restrict__ c0)
{
    __shared__ float T[64][65];
    const int b = blockIdx.x;
    const int tid = threadIdx.x;
    if (b < 1056) {                       // X cast: 8 elems/thread
        const int e0 = b * 2048 + tid * 8;
        const int row = e0 >> 9, c = e0 & 511;
        float v[8];
        if (row < NTOK) {
            const float4 a0 = *(const float4*)&patch[(size_t)row * DD + c];
            const float4 a1 = *(const float4*)&patch[(size_t)row * DD + c + 4];
            v[0]=a0.x; v[1]=a0.y; v[2]=a0.z; v[3]=a0.w;
            v[4]=a1.x; v[5]=a1.y; v[6]=a1.z; v[7]=a1.w;
        } else if (row < MEXT) {
            const float4 a0 = *(const float4*)&query[(size_t)(row - NTOK) * DD + c];
            const float4 a1 = *(const float4*)&query[(size_t)(row - NTOK) * DD + c + 4];
            v[0]=a0.x; v[1]=a0.y; v[2]=a0.z; v[3]=a0.w;
            v[4]=a1.x; v[5]=a1.y; v[6]=a1.z; v[7]=a1.w;
        } else {
#pragma unroll
            for (int j = 0; j < 8; ++j) v[j] = 0.f;
        }
        ushort o[8];
#pragma unroll
        for (int j = 0; j < 8; ++j) o[j] = f2bf(v[j]);
        *(uint4*)&Xb[e0] = *(const uint4*)o;
    } else if (b < 1120) {                // Wv transpose, 64x64 tile
        const int t = b - 1056;
        const int k0 = (t >> 3) * 64, n0 = (t & 7) * 64;
#pragma unroll
        for (int j = 0; j < 16; ++j) {
            const int idx = tid + j * 256;
            const int r = idx >> 6, c = idx & 63;
            T[r][c] = Wv[(size_t)(k0 + r) * DD + n0 + c];
        }
        __syncthreads();
#pragma unroll
        for (int j = 0; j < 16; ++j) {
            const int idx = tid + j * 256;
            const int r = idx >> 6, c = idx & 63;
            Bb[(size_t)(n0 + r) * DD + k0 + c] = f2bf(T[c][r]);
        }
    } else if (b < 1132) {                // zero rows 528..575
        const int e0 = (b - 1120) * 2048 + tid * 8;
        *(uint4*)&Bb[(size_t)528 * DD + e0] = make_uint4(0, 0, 0, 0);
    } else {                              // A (score B-rows) + c0
        const int wave = tid >> 6, lane = tid & 63;
        const int g = (b - 1132) * 4 + wave;
        if (g < DD) {
            const int e = g;
            float x[8];
#pragma unroll
            for (int j = 0; j < 8; ++j) x[j] = Wk[e * DD + j * 64 + lane];
            for (int q = 0; q < QN; ++q) {
                float s = 0.f;
#pragma unroll
                for (int j = 0; j < 8; ++j) s += x[j] * query[q * DD + j * 64 + lane];
#pragma unroll
                for (int off = 32; off > 0; off >>= 1) s += __shfl_down(s, off, 64);
                if (lane == 0) Bb[(size_t)(DD + q) * DD + e] = f2bf(s);
            }
        } else {
            const int q = g - DD;
            float s = 0.f;
#pragma unroll
            for (int j = 0; j < 8; ++j)
                s += bk[j * 64 + lane] * query[q * DD + j * 64 + lane];
#pragma unroll
            for (int off = 32; off > 0; off >>= 1) s += __shfl_down(s, off, 64);
            if (lane == 0) c0[q] = s;
        }
    }
}

// ---------------------------------------------------------------------------
// K2: fused MFMA GEMM  C[4224 x 576] = Xb @ Bb^T  (Bb stored [n][k])
//   cols 0..511   -> VpH bf16 (+ bv);  cols 512..527 -> S fp32 ((acc+c0)*SCALE)
// 64x64 tile, 4 waves (2x2 of 32x32), BK=64, 16x16x32 bf16 MFMA, grid (9,66).
// R3-verified staging (gload_lds w=16 both sides, linear LDS dest +
// pre-swizzled source, byte ^= (row&7)<<4 on all paths) + 2-phase double
// buffer (T3-minimum): per K-step, issue the 4 staging loads for tile t+1
// BEFORE the MFMA cluster on tile t, single __syncthreads per step. The
// barrier's vmcnt(0) then only pays max(0, load_latency - compute_time)
// instead of the full load latency 8x per block (R3's serial order).
// ---------------------------------------------------------------------------
__global__ __launch_bounds__(256) void k2_mfma(
    const ushort* __restrict__ Xb, const ushort* __restrict__ Bb,
    const float* __restrict__ bv, const float* __restrict__ c0,
    ushort* __restrict__ VpH, float* __restrict__ S)
{
    __shared__ __align__(16) ushort Xs[2][4096];   // 2 x 8KB, swizzled
    __shared__ __align__(16) ushort Bs[2][4096];
    const int tid = threadIdx.x;
    const int rowBase = blockIdx.y * 64;
    const int colBase = blockIdx.x * 64;
    const int wave = tid >> 6, lane = tid & 63;
    const int wm = (wave >> 1) * 32, wn = (wave & 1) * 32;
    const int lr = lane & 15;
    const int quad = lane >> 4;

    // staging constants: 2 issues x 256 lanes x 16B cover one 8KB buffer
    const int L0 = tid * 16;
    const int L1 = 4096 + tid * 16;
    const int r0s = L0 >> 7, c0s = (L0 & 127) ^ ((r0s & 7) << 4);
    const int r1s = L1 >> 7, c1s = (L1 & 127) ^ ((r1s & 7) << 4);
    const char* gX0 = (const char*)&Xb[(size_t)(rowBase + r0s) * DD] + c0s;
    const char* gX1 = (const char*)&Xb[(size_t)(rowBase + r1s) * DD] + c1s;
    const char* gB0 = (const char*)&Bb[(size_t)(colBase + r0s) * DD] + c0s;
    const char* gB1 = (const char*)&Bb[(size_t)(colBase + r1s) * DD] + c1s;

    char* XsB = (char*)Xs;
    char* BsB = (char*)Bs;

    f32x4 acc[2][2];
    const f32x4 zero = {0.f, 0.f, 0.f, 0.f};
#pragma unroll
    for (int i = 0; i < 2; ++i) { acc[i][0] = zero; acc[i][1] = zero; }

    // prologue: stage K-step 0 into buf 0
    gload16(gX0, XsB + L0);
    gload16(gX1, XsB + L1);
    gload16(gB0, BsB + L0);
    gload16(gB1, BsB + L1);
    __syncthreads();

#pragma unroll
    for (int t = 0; t < 8; ++t) {
        const int buf = t & 1, nxt = buf ^ 1;
        if (t < 7) {                          // issue-early: stage t+1 into nxt
            const int kB = (t + 1) * 128;     // 64 bf16 = 128 bytes per K-step
            gload16(gX0 + kB, XsB + nxt * 8192 + L0);
            gload16(gX1 + kB, XsB + nxt * 8192 + L1);
            gload16(gB0 + kB, BsB + nxt * 8192 + L0);
            gload16(gB1 + kB, BsB + nxt * 8192 + L1);
        }
        const int BF = buf * 8192;
#pragma unroll
        for (int kc = 0; kc < 2; ++kc) {
            bf16x8 af[2], bfr[2];
#pragma unroll
            for (int m = 0; m < 2; ++m) {
                const int ar = wm + m * 16 + lr;
                const int ab = (ar * 128 + kc * 64 + quad * 16) ^ ((ar & 7) << 4);
                af[m] = *(const bf16x8*)(XsB + BF + ab);
            }
#pragma unroll
            for (int u = 0; u < 2; ++u) {
                const int br = wn + u * 16 + lr;
                const int bb = (br * 128 + kc * 64 + quad * 16) ^ ((br & 7) << 4);
                bfr[u] = *(const bf16x8*)(BsB + BF + bb);
            }
#pragma unroll
            for (int mt = 0; mt < 2; ++mt)
#pragma unroll
                for (int nt = 0; nt < 2; ++nt)
                    acc[mt][nt] = __builtin_amdgcn_mfma_f32_16x16x32_bf16(
                        af[mt], bfr[nt], acc[mt][nt], 0, 0, 0);
        }
        __syncthreads();
    }

    // epilogue: C/D layout col = lane&15, row = quad*4 + r (m89/m91)
#pragma unroll
    for (int nt = 0; nt < 2; ++nt) {
        const int col = colBase + wn + nt * 16 + lr;
        const bool isV = (col < DD);
        const bool isS = (col >= DD) && (col < DD + QN);
        const float badd = isV ? bv[col] : (isS ? c0[col - DD] : 0.f);
#pragma unroll
        for (int mt = 0; mt < 2; ++mt) {
#pragma unroll
            for (int r = 0; r < 4; ++r) {
                const int row = rowBase + wm + mt * 16 + quad * 4 + r;
                if (row < MEXT) {
                    const float v = acc[mt][nt][r];
                    if (isV)      VpH[(size_t)row * DD + col] = f2bf(v + badd);
                    else if (isS) S[row * QN + (col - DD)] = (v + badd) * SCALE;
                }
            }
        }
    }
}

// ---------------------------------------------------------------------------
// K4: per-group aggregation. Vp gathered as bf16 (4.2 MB, L2/L3-resident).
// Weights p-major in LDS (scT[p][q]) -> broadcast float4 reads, conflict-free.
// Gather loop 8-deep (R3-verified).
// ---------------------------------------------------------------------------
__global__ __launch_bounds__(256) void k4_agg(
    const ushort* __restrict__ VpH,    // MEXT x D bf16 (rows >= NTOK are VQ)
    const float* __restrict__ S,       // MEXT x QN
    const int* __restrict__ indices,
    const void* __restrict__ pmask,
    const float* __restrict__ Wf, const float* __restrict__ bf,
    float* __restrict__ out)
{
    __shared__ int   idxs[PP];
    __shared__ int   mval[PP];
    __shared__ int   cidx[PP + 8];
    __shared__ int   cp[PP + 8];
    __shared__ float scT[PP + 2][QN];  // row0=self, 1..64=gathered, 65=zero pad
    __shared__ float red[QN][4];
    __shared__ float fwq[QN];
    __shared__ int   cntS;

    const int n = blockIdx.x;
    const int tid = threadIdx.x;

    // pos_mask storage-width detection (wave-uniform)
    const unsigned int* mw = (const unsigned int*)pmask;
    bool four = true;
#pragma unroll
    for (int i = 0; i < 16; ++i) {
        const unsigned int v = mw[i];
        four = four && (v == 0u || v == 1u || v == 0x3F800000u);
    }

    if (tid < PP) {
        idxs[tid] = indices[n * PP + tid];
        int mv;
        if (four) mv = (mw[n * PP + tid] != 0u);
        else      mv = (((const unsigned char*)pmask)[n * PP + tid] != 0);
        mval[tid] = mv;
        const bool a = (mv != 0);
        const unsigned long long m = __ballot(a);
        const int pos = __popcll(m & ((1ull << tid) - 1ull));
        if (a) { cidx[pos] = idxs[tid]; cp[pos] = tid; }
        if (tid == 0) cntS = (int)__popcll(m);
    }
    __syncthreads();

    // gather scores (p-major), full 1024-entry fill
    for (int e = tid; e < QN * PP; e += 256) {
        const int p = e >> 4, q = e & 15;
        scT[p + 1][q] = mval[p] ? S[idxs[p] * QN + q] : -INFINITY;
    }
    if (tid < QN) scT[0][tid] = S[(NTOK + tid) * QN + tid];   // s_self[q]
    __syncthreads();

    if (tid < 8) { cidx[cntS + tid] = 0; cp[cntS + tid] = PP; }  // pad entries
    if (tid < QN) {                                  // softmax over 65 per q
        const int q = tid;
        float m = -INFINITY;
        for (int j = 0; j <= PP; ++j) m = fmaxf(m, scT[j][q]);
        float s = 0.f;
        for (int j = 0; j <= PP; ++j) { const float e = __expf(scT[j][q] - m); scT[j][q] = e; s += e; }
        const float inv = 1.f / s;
        for (int j = 0; j <= PP; ++j) scT[j][q] *= inv;
        scT[PP + 1][q] = 0.f;                        // pad weight = 0
    }
    __syncthreads();

    const int cnt8 = (cntS + 7) & ~7;
    const int d0 = tid * 2;
    float pt[QN][2];
    {
        float2 vq[QN];
#pragma unroll
        for (int q = 0; q < QN; ++q)
            vq[q] = bfp2f2(*(const unsigned int*)&VpH[(size_t)(NTOK + q) * DD + d0]);
#pragma unroll
        for (int q = 0; q < QN; ++q) {
            const float w0 = scT[0][q];
            pt[q][0] = w0 * vq[q].x;
            pt[q][1] = w0 * vq[q].y;
        }
    }
    for (int j0 = 0; j0 < cnt8; j0 += 8) {
        float2 v[8]; int p[8];
#pragma unroll
        for (int pi = 0; pi < 8; ++pi) {
            v[pi] = bfp2f2(*(const unsigned int*)&VpH[(size_t)cidx[j0 + pi] * DD + d0]);
            p[pi] = cp[j0 + pi] + 1;
        }
#pragma unroll
        for (int pi = 0; pi < 8; ++pi) {
            const float4 wa = *(const float4*)&scT[p[pi]][0];
            const float4 wb = *(const float4*)&scT[p[pi]][4];
            const float4 wc = *(const float4*)&scT[p[pi]][8];
            const float4 wd = *(const float4*)&scT[p[pi]][12];
            const float vx = v[pi].x, vy = v[pi].y;
            pt[ 0][0] += wa.x*vx; pt[ 0][1] += wa.x*vy;
            pt[ 1][0] += wa.y*vx; pt[ 1][1] += wa.y*vy;
            pt[ 2][0] += wa.z*vx; pt[ 2][1] += wa.z*vy;
            pt[ 3][0] += wa.w*vx; pt[ 3][1] += wa.w*vy;
            pt[ 4][0] += wb.x*vx; pt[ 4][1] += wb.x*vy;
            pt[ 5][0] += wb.y*vx; pt[ 5][1] += wb.y*vy;
            pt[ 6][0] += wb.z*vx; pt[ 6][1] += wb.z*vy;
            pt[ 7][0] += wb.w*vx; pt[ 7][1] += wb.w*vy;
            pt[ 8][0] += wc.x*vx; pt[ 8][1] += wc.x*vy;
            pt[ 9][0] += wc.y*vx; pt[ 9][1] += wc.y*vy;
            pt[10][0] += wc.z*vx; pt[10][1] += wc.z*vy;
            pt[11][0] += wc.w*vx; pt[11][1] += wc.w*vy;
            pt[12][0] += wd.x*vx; pt[12][1] += wd.x*vy;
            pt[13][0] += wd.y*vx; pt[13][1] += wd.y*vy;
            pt[14][0] += wd.z*vx; pt[14][1] += wd.z*vy;
            pt[15][0] += wd.w*vx; pt[15][1] += wd.w*vy;
        }
    }

    // fusion logits f[q] = pt[q,:] . Wf + bf
    const float wf0 = Wf[d0], wf1 = Wf[d0 + 1];
    const int wid = tid >> 6, lane = tid & 63;
#pragma unroll
    for (int q = 0; q < QN; ++q) {
        float s = pt[q][0] * wf0 + pt[q][1] * wf1;
#pragma unroll
        for (int off = 32; off > 0; off >>= 1) s += __shfl_down(s, off, 64);
        if (lane == 0) red[q][wid] = s;
    }
    __syncthreads();
    if (tid == 0) {
        float f[QN];
        float m = -INFINITY;
#pragma unroll
        for (int q = 0; q < QN; ++q) {
            f[q] = red[q][0] + red[q][1] + red[q][2] + red[q][3] + bf[0];
            m = fmaxf(m, f[q]);
        }
        float ssum = 0.f;
#pragma unroll
        for (int q = 0; q < QN; ++q) { f[q] = __expf(f[q] - m); ssum += f[q]; }
        const float inv = 1.f / ssum;
#pragma unroll
        for (int q = 0; q < QN; ++q) fwq[q] = f[q] * inv;
    }
    __syncthreads();

    float o0 = 0.f, o1 = 0.f;
#pragma unroll
    for (int q = 0; q < QN; ++q) {
        const float w = fwq[q];
        o0 += pt[q][0] * w;
        o1 += pt[q][1] * w;
    }
    *(float2*)&out[(size_t)n * DD + d0] = make_float2(o0, o1);
}

// ---------------------------------------------------------------------------
extern "C" void kernel_launch(void* const* d_in, const int* in_sizes, int n_in,
                              void* d_out, int out_size, void* d_ws, size_t ws_size,
                              hipStream_t stream)
{
    const float* patch   = (const float*)d_in[0];
    const float* query   = (const float*)d_in[1];
    const float* Wk      = (const float*)d_in[2];
    const float* bk      = (const float*)d_in[3];
    const float* Wv      = (const float*)d_in[4];
    const float* bv      = (const float*)d_in[5];
    const float* Wf      = (const float*)d_in[6];
    const float* bf      = (const float*)d_in[7];
    const int*   indices = (const int*)d_in[8];
    const void*  pmask   = d_in[9];
    float* out = (float*)d_out;

    // ws: VpH bf16[MEXT*DD] | S f32[MEXT*QN] | c0 f32[16]
    //     | Xb bf16[MPAD*DD] | Bb bf16[NB*DD]     (~9.4 MB of 256 MiB ws)
    ushort* VpH = (ushort*)d_ws;
    float*  S   = (float*)(VpH + (size_t)MEXT * DD);
    float*  c0  = S + (size_t)MEXT * QN;
    ushort* Xb  = (ushort*)(c0 + 16);
    ushort* Bb  = Xb + (size_t)MPAD * DD;

    pack_all<<<dim3(1264), dim3(256), 0, stream>>>(patch, query, Wv, Wk, bk, Xb, Bb, c0);
    k2_mfma <<<dim3(9, 66), dim3(256), 0, stream>>>(Xb, Bb, bv, c0, VpH, S);
    k4_agg  <<<dim3(NGRP), dim3(256), 0, stream>>>(VpH, S, indices, pmask, Wf, bf, out);
}

// Round 8
// 116.071 us; speedup vs baseline: 1.0490x; 1.0353x over previous
//
#include <hip/hip_runtime.h>
#include <hip/hip_bf16.h>
#include <math.h>

// Problem constants: B=32, L=128, D=512, Qn=16, N=512, P=64
#define DD    512
#define QN    16
#define NTOK  4096
#define MEXT  4112           // NTOK + QN
#define MPAD  4224           // 66 * 64
#define NGRP  512
#define PP    64
#define NB    576            // padded B rows: 512 Wv + 16 score + 48 pad (9 tiles)
#define SCALE 0.04419417382415922f   // 1/sqrt(512)

typedef __bf16 bf16x8 __attribute__((ext_vector_type(8)));
typedef float  f32x4  __attribute__((ext_vector_type(4)));

static __device__ __forceinline__ ushort f2bf(float f) {
    __hip_bfloat16 h = __float2bfloat16(f);
    return *reinterpret_cast<ushort*>(&h);
}
// unpack 2 packed bf16 (little-endian: low ushort = element 0) to fp32
static __device__ __forceinline__ float2 bfp2f2(unsigned int v) {
    float2 r;
    r.x = __uint_as_float(v << 16);
    r.y = __uint_as_float(v & 0xffff0000u);
    return r;
}
// async global->LDS, 16B per lane (HW: wave-uniform LDS base + lane*16)
static __device__ __forceinline__ void gload16(const void* g, void* l) {
    __builtin_amdgcn_global_load_lds(
        (const __attribute__((address_space(1))) void*)g,
        (__attribute__((address_space(3))) void*)l, 16, 0, 0);
}

// ---------------------------------------------------------------------------
// pack_all: one kernel, block-range dispatch (no cross-range dependencies).
//  [0,1056)    : Xb = bf16([patch ; Q0 ; zeros])              (4224 x 512)
//  [1056,1120) : Bb rows 0..511   = bf16(Wv^T)  (64x64 LDS-tile transpose)
//  [1120,1132) : Bb rows 528..575 = 0
//  [1132,1264) : Bb rows 512..527 = bf16(Wk @ Q0^T), + c0[q] = bk.Q0[q]
// (R3-verified version)
// ---------------------------------------------------------------------------
__global__ __launch_bounds__(256) void pack_all(
    const float* __restrict__ patch, const float* __restrict__ query,
    const float* __restrict__ Wv, const float* __restrict__ Wk,
    const float* __restrict__ bk,
    ushort* __restrict__ Xb, ushort* __restrict__ Bb, float* __restrict__ c0)
{
    __shared__ float T[64][65];
    const int b = blockIdx.x;
    const int tid = threadIdx.x;
    if (b < 1056) {                       // X cast: 8 elems/thread
        const int e0 = b * 2048 + tid * 8;
        const int row = e0 >> 9, c = e0 & 511;
        float v[8];
        if (row < NTOK) {
            const float4 a0 = *(const float4*)&patch[(size_t)row * DD + c];
            const float4 a1 = *(const float4*)&patch[(size_t)row * DD + c + 4];
            v[0]=a0.x; v[1]=a0.y; v[2]=a0.z; v[3]=a0.w;
            v[4]=a1.x; v[5]=a1.y; v[6]=a1.z; v[7]=a1.w;
        } else if (row < MEXT) {
            const float4 a0 = *(const float4*)&query[(size_t)(row - NTOK) * DD + c];
            const float4 a1 = *(const float4*)&query[(size_t)(row - NTOK) * DD + c + 4];
            v[0]=a0.x; v[1]=a0.y; v[2]=a0.z; v[3]=a0.w;
            v[4]=a1.x; v[5]=a1.y; v[6]=a1.z; v[7]=a1.w;
        } else {
#pragma unroll
            for (int j = 0; j < 8; ++j) v[j] = 0.f;
        }
        ushort o[8];
#pragma unroll
        for (int j = 0; j < 8; ++j) o[j] = f2bf(v[j]);
        *(uint4*)&Xb[e0] = *(const uint4*)o;
    } else if (b < 1120) {                // Wv transpose, 64x64 tile
        const int t = b - 1056;
        const int k0 = (t >> 3) * 64, n0 = (t & 7) * 64;
#pragma unroll
        for (int j = 0; j < 16; ++j) {
            const int idx = tid + j * 256;
            const int r = idx >> 6, c = idx & 63;
            T[r][c] = Wv[(size_t)(k0 + r) * DD + n0 + c];
        }
        __syncthreads();
#pragma unroll
        for (int j = 0; j < 16; ++j) {
            const int idx = tid + j * 256;
            const int r = idx >> 6, c = idx & 63;
            Bb[(size_t)(n0 + r) * DD + k0 + c] = f2bf(T[c][r]);
        }
    } else if (b < 1132) {                // zero rows 528..575
        const int e0 = (b - 1120) * 2048 + tid * 8;
        *(uint4*)&Bb[(size_t)528 * DD + e0] = make_uint4(0, 0, 0, 0);
    } else {                              // A (score B-rows) + c0
        const int wave = tid >> 6, lane = tid & 63;
        const int g = (b - 1132) * 4 + wave;
        if (g < DD) {
            const int e = g;
            float x[8];
#pragma unroll
            for (int j = 0; j < 8; ++j) x[j] = Wk[e * DD + j * 64 + lane];
            for (int q = 0; q < QN; ++q) {
                float s = 0.f;
#pragma unroll
                for (int j = 0; j < 8; ++j) s += x[j] * query[q * DD + j * 64 + lane];
#pragma unroll
                for (int off = 32; off > 0; off >>= 1) s += __shfl_down(s, off, 64);
                if (lane == 0) Bb[(size_t)(DD + q) * DD + e] = f2bf(s);
            }
        } else {
            const int q = g - DD;
            float s = 0.f;
#pragma unroll
            for (int j = 0; j < 8; ++j)
                s += bk[j * 64 + lane] * query[q * DD + j * 64 + lane];
#pragma unroll
            for (int off = 32; off > 0; off >>= 1) s += __shfl_down(s, off, 64);
            if (lane == 0) c0[q] = s;
        }
    }
}

// ---------------------------------------------------------------------------
// K2: fused MFMA GEMM  C[4224 x 576] = Xb @ Bb^T  (Bb stored [n][k])
//   cols 0..511   -> VpH bf16 (+ bv);  cols 512..527 -> S fp32 ((acc+c0)*SCALE)
// 64x64 tile, 4 waves (2x2 of 32x32), BK=64, 16x16x32 bf16 MFMA.
// R3-verified staging (gload_lds w=16 both sides, linear LDS dest +
// pre-swizzled source, byte ^= (row&7)<<4 on all paths).
// NEW (T1, m204): 1D grid 594 + bijective XCD swizzle. HW assigns block
// `flat` to XCD flat%8; remap so each XCD owns ~75 CONSECUTIVE logical
// tiles (~8 full row-strips): per strip the 64KB Xb A-panel is 1 L3 miss
// + 8 L2 hits instead of 9 cross-XCD fetches. q=594/8=74, r=594%8=2.
// ---------------------------------------------------------------------------
__global__ __launch_bounds__(256) void k2_mfma(
    const ushort* __restrict__ Xb, const ushort* __restrict__ Bb,
    const float* __restrict__ bv, const float* __restrict__ c0,
    ushort* __restrict__ VpH, float* __restrict__ S)
{
    __shared__ __align__(16) ushort Xs[64 * 64];   // linear, swizzled
    __shared__ __align__(16) ushort Bs[64 * 64];
    const int tid = threadIdx.x;

    // bijective XCD swizzle (594 = 2*75 + 6*74)
    const int flat = (int)blockIdx.x;
    const int xcd  = flat & 7;
    const int wgid = (xcd < 2 ? xcd * 75 : 150 + (xcd - 2) * 74) + (flat >> 3);
    const int rowBase = (wgid / 9) * 64;
    const int colBase = (wgid % 9) * 64;

    const int wave = tid >> 6, lane = tid & 63;
    const int wm = (wave >> 1) * 32, wn = (wave & 1) * 32;
    const int lr = lane & 15;
    const int quad = lane >> 4;

    f32x4 acc[2][2];
    const f32x4 zero = {0.f, 0.f, 0.f, 0.f};
#pragma unroll
    for (int i = 0; i < 2; ++i) { acc[i][0] = zero; acc[i][1] = zero; }

    char* XsB = (char*)Xs;
    char* BsB = (char*)Bs;

    for (int k0 = 0; k0 < DD; k0 += 64) {
        // stage 8KB per array: 2 issues x 256 lanes x 16B. LDS dest linear;
        // global source pre-swizzled so that swizzled ds_read returns X[r][c].
#pragma unroll
        for (int i = 0; i < 2; ++i) {
            const int L = i * 4096 + tid * 16;            // LDS byte offset
            const int r = L >> 7;                          // row 0..63
            const int cB = (L & 127) ^ ((r & 7) << 4);     // source byte col
            gload16((const char*)&Xb[(size_t)(rowBase + r) * DD + k0] + cB, XsB + L);
            gload16((const char*)&Bb[(size_t)(colBase + r) * DD + k0] + cB, BsB + L);
        }
        __syncthreads();   // compiler emits vmcnt(0) drain before s_barrier
#pragma unroll
        for (int kc = 0; kc < 2; ++kc) {
            bf16x8 af[2], bfr[2];
#pragma unroll
            for (int t = 0; t < 2; ++t) {
                const int ar = wm + t * 16 + lr;
                const int ab = (ar * 128 + kc * 64 + quad * 16) ^ ((ar & 7) << 4);
                af[t] = *(const bf16x8*)(XsB + ab);
            }
#pragma unroll
            for (int u = 0; u < 2; ++u) {
                const int br = wn + u * 16 + lr;
                const int bb = (br * 128 + kc * 64 + quad * 16) ^ ((br & 7) << 4);
                bfr[u] = *(const bf16x8*)(BsB + bb);
            }
#pragma unroll
            for (int mt = 0; mt < 2; ++mt)
#pragma unroll
                for (int nt = 0; nt < 2; ++nt)
                    acc[mt][nt] = __builtin_amdgcn_mfma_f32_16x16x32_bf16(
                        af[mt], bfr[nt], acc[mt][nt], 0, 0, 0);
        }
        __syncthreads();
    }

    // epilogue: C/D layout col = lane&15, row = quad*4 + r (m89/m91)
#pragma unroll
    for (int nt = 0; nt < 2; ++nt) {
        const int col = colBase + wn + nt * 16 + lr;
        const bool isV = (col < DD);
        const bool isS = (col >= DD) && (col < DD + QN);
        const float badd = isV ? bv[col] : (isS ? c0[col - DD] : 0.f);
#pragma unroll
        for (int mt = 0; mt < 2; ++mt) {
#pragma unroll
            for (int r = 0; r < 4; ++r) {
                const int row = rowBase + wm + mt * 16 + quad * 4 + r;
                if (row < MEXT) {
                    const float v = acc[mt][nt][r];
                    if (isV)      VpH[(size_t)row * DD + col] = f2bf(v + badd);
                    else if (isS) S[row * QN + (col - DD)] = (v + badd) * SCALE;
                }
            }
        }
    }
}

// ---------------------------------------------------------------------------
// K4: per-group aggregation. Vp gathered as bf16 (4.2 MB, L2/L3-resident).
// Weights p-major in LDS (scT[p][q]) -> broadcast float4 reads, conflict-free.
// Gather loop 8-deep (R3-verified).
// ---------------------------------------------------------------------------
__global__ __launch_bounds__(256) void k4_agg(
    const ushort* __restrict__ VpH,    // MEXT x D bf16 (rows >= NTOK are VQ)
    const float* __restrict__ S,       // MEXT x QN
    const int* __restrict__ indices,
    const void* __restrict__ pmask,
    const float* __restrict__ Wf, const float* __restrict__ bf,
    float* __restrict__ out)
{
    __shared__ int   idxs[PP];
    __shared__ int   mval[PP];
    __shared__ int   cidx[PP + 8];
    __shared__ int   cp[PP + 8];
    __shared__ float scT[PP + 2][QN];  // row0=self, 1..64=gathered, 65=zero pad
    __shared__ float red[QN][4];
    __shared__ float fwq[QN];
    __shared__ int   cntS;

    const int n = blockIdx.x;
    const int tid = threadIdx.x;

    // pos_mask storage-width detection (wave-uniform)
    const unsigned int* mw = (const unsigned int*)pmask;
    bool four = true;
#pragma unroll
    for (int i = 0; i < 16; ++i) {
        const unsigned int v = mw[i];
        four = four && (v == 0u || v == 1u || v == 0x3F800000u);
    }

    if (tid < PP) {
        idxs[tid] = indices[n * PP + tid];
        int mv;
        if (four) mv = (mw[n * PP + tid] != 0u);
        else      mv = (((const unsigned char*)pmask)[n * PP + tid] != 0);
        mval[tid] = mv;
        const bool a = (mv != 0);
        const unsigned long long m = __ballot(a);
        const int pos = __popcll(m & ((1ull << tid) - 1ull));
        if (a) { cidx[pos] = idxs[tid]; cp[pos] = tid; }
        if (tid == 0) cntS = (int)__popcll(m);
    }
    __syncthreads();

    // gather scores (p-major), full 1024-entry fill
    for (int e = tid; e < QN * PP; e += 256) {
        const int p = e >> 4, q = e & 15;
        scT[p + 1][q] = mval[p] ? S[idxs[p] * QN + q] : -INFINITY;
    }
    if (tid < QN) scT[0][tid] = S[(NTOK + tid) * QN + tid];   // s_self[q]
    __syncthreads();

    if (tid < 8) { cidx[cntS + tid] = 0; cp[cntS + tid] = PP; }  // pad entries
    if (tid < QN) {                                  // softmax over 65 per q
        const int q = tid;
        float m = -INFINITY;
        for (int j = 0; j <= PP; ++j) m = fmaxf(m, scT[j][q]);
        float s = 0.f;
        for (int j = 0; j <= PP; ++j) { const float e = __expf(scT[j][q] - m); scT[j][q] = e; s += e; }
        const float inv = 1.f / s;
        for (int j = 0; j <= PP; ++j) scT[j][q] *= inv;
        scT[PP + 1][q] = 0.f;                        // pad weight = 0
    }
    __syncthreads();

    const int cnt8 = (cntS + 7) & ~7;
    const int d0 = tid * 2;
    float pt[QN][2];
    {
        float2 vq[QN];
#pragma unroll
        for (int q = 0; q < QN; ++q)
            vq[q] = bfp2f2(*(const unsigned int*)&VpH[(size_t)(NTOK + q) * DD + d0]);
#pragma unroll
        for (int q = 0; q < QN; ++q) {
            const float w0 = scT[0][q];
            pt[q][0] = w0 * vq[q].x;
            pt[q][1] = w0 * vq[q].y;
        }
    }
    for (int j0 = 0; j0 < cnt8; j0 += 8) {
        float2 v[8]; int p[8];
#pragma unroll
        for (int pi = 0; pi < 8; ++pi) {
            v[pi] = bfp2f2(*(const unsigned int*)&VpH[(size_t)cidx[j0 + pi] * DD + d0]);
            p[pi] = cp[j0 + pi] + 1;
        }
#pragma unroll
        for (int pi = 0; pi < 8; ++pi) {
            const float4 wa = *(const float4*)&scT[p[pi]][0];
            const float4 wb = *(const float4*)&scT[p[pi]][4];
            const float4 wc = *(const float4*)&scT[p[pi]][8];
            const float4 wd = *(const float4*)&scT[p[pi]][12];
            const float vx = v[pi].x, vy = v[pi].y;
            pt[ 0][0] += wa.x*vx; pt[ 0][1] += wa.x*vy;
            pt[ 1][0] += wa.y*vx; pt[ 1][1] += wa.y*vy;
            pt[ 2][0] += wa.z*vx; pt[ 2][1] += wa.z*vy;
            pt[ 3][0] += wa.w*vx; pt[ 3][1] += wa.w*vy;
            pt[ 4][0] += wb.x*vx; pt[ 4][1] += wb.x*vy;
            pt[ 5][0] += wb.y*vx; pt[ 5][1] += wb.y*vy;
            pt[ 6][0] += wb.z*vx; pt[ 6][1] += wb.z*vy;
            pt[ 7][0] += wb.w*vx; pt[ 7][1] += wb.w*vy;
            pt[ 8][0] += wc.x*vx; pt[ 8][1] += wc.x*vy;
            pt[ 9][0] += wc.y*vx; pt[ 9][1] += wc.y*vy;
            pt[10][0] += wc.z*vx; pt[10][1] += wc.z*vy;
            pt[11][0] += wc.w*vx; pt[11][1] += wc.w*vy;
            pt[12][0] += wd.x*vx; pt[12][1] += wd.x*vy;
            pt[13][0] += wd.y*vx; pt[13][1] += wd.y*vy;
            pt[14][0] += wd.z*vx; pt[14][1] += wd.z*vy;
            pt[15][0] += wd.w*vx; pt[15][1] += wd.w*vy;
        }
    }

    // fusion logits f[q] = pt[q,:] . Wf + bf
    const float wf0 = Wf[d0], wf1 = Wf[d0 + 1];
    const int wid = tid >> 6, lane = tid & 63;
#pragma unroll
    for (int q = 0; q < QN; ++q) {
        float s = pt[q][0] * wf0 + pt[q][1] * wf1;
#pragma unroll
        for (int off = 32; off > 0; off >>= 1) s += __shfl_down(s, off, 64);
        if (lane == 0) red[q][wid] = s;
    }
    __syncthreads();
    if (tid == 0) {
        float f[QN];
        float m = -INFINITY;
#pragma unroll
        for (int q = 0; q < QN; ++q) {
            f[q] = red[q][0] + red[q][1] + red[q][2] + red[q][3] + bf[0];
            m = fmaxf(m, f[q]);
        }
        float ssum = 0.f;
#pragma unroll
        for (int q = 0; q < QN; ++q) { f[q] = __expf(f[q] - m); ssum += f[q]; }
        const float inv = 1.f / ssum;
#pragma unroll
        for (int q = 0; q < QN; ++q) fwq[q] = f[q] * inv;
    }
    __syncthreads();

    float o0 = 0.f, o1 = 0.f;
#pragma unroll
    for (int q = 0; q < QN; ++q) {
        const float w = fwq[q];
        o0 += pt[q][0] * w;
        o1 += pt[q][1] * w;
    }
    *(float2*)&out[(size_t)n * DD + d0] = make_float2(o0, o1);
}

// ---------------------------------------------------------------------------
extern "C" void kernel_launch(void* const* d_in, const int* in_sizes, int n_in,
                              void* d_out, int out_size, void* d_ws, size_t ws_size,
                              hipStream_t stream)
{
    const float* patch   = (const float*)d_in[0];
    const float* query   = (const float*)d_in[1];
    const float* Wk      = (const float*)d_in[2];
    const float* bk      = (const float*)d_in[3];
    const float* Wv      = (const float*)d_in[4];
    const float* bv      = (const float*)d_in[5];
    const float* Wf      = (const float*)d_in[6];
    const float* bf      = (const float*)d_in[7];
    const int*   indices = (const int*)d_in[8];
    const void*  pmask   = d_in[9];
    float* out = (float*)d_out;

    // ws: VpH bf16[MEXT*DD] | S f32[MEXT*QN] | c0 f32[16]
    //     | Xb bf16[MPAD*DD] | Bb bf16[NB*DD]     (~9.4 MB of 256 MiB ws)
    ushort* VpH = (ushort*)d_ws;
    float*  S   = (float*)(VpH + (size_t)MEXT * DD);
    float*  c0  = S + (size_t)MEXT * QN;
    ushort* Xb  = (ushort*)(c0 + 16);
    ushort* Bb  = Xb + (size_t)MPAD * DD;

    pack_all<<<dim3(1264), dim3(256), 0, stream>>>(patch, query, Wv, Wk, bk, Xb, Bb, c0);
    k2_mfma <<<dim3(594), dim3(256), 0, stream>>>(Xb, Bb, bv, c0, VpH, S);
    k4_agg  <<<dim3(NGRP), dim3(256), 0, stream>>>(VpH, S, indices, pmask, Wf, bf, out);
}